// Round 1
// baseline (51.200 us; speedup 1.0000x reference)
//
#include <hip/hip_runtime.h>

#define NEG_BIG (-1e30f)

// offsets are compile-time constants -> fully unrolled, address math constant-folded
__device__ __constant__ const int OFFS_dummy = 0; // (unused; offsets inlined below)

__global__ __launch_bounds__(256) void dsqg_attn_kernel(
    const float* __restrict__ q, const float* __restrict__ k,
    const float* __restrict__ v, const float* __restrict__ pb,
    const float* __restrict__ se, float* __restrict__ out)
{
    constexpr int OFFS[16] = {1, 3, 4, 13, 15, 21, 23, 28, 48, 64, 96, 192, 384, 512, 768, 1024};
    // grid: 16 heads * 256 blocks/head = 4096 blocks; block: 256 threads = 16 queries * 16 lanes
    const int h = blockIdx.x >> 8;                                // uniform per block -> SGPR
    const int n = ((blockIdx.x & 255) << 4) + (threadIdx.x >> 4); // query index in [0,4096)
    const int j = threadIdx.x & 15;                               // dim-chunk lane: dims [4j, 4j+4)
    const size_t head_base = (size_t)h << 18;                     // h * 4096 * 64
    const size_t qoff = head_base + ((size_t)n << 6) + (j << 2);

    const float4 qv = *(const float4*)(q + qoff);

    float s[16];
#pragma unroll
    for (int i = 0; i < 16; ++i) {
        const int off  = OFFS[i];
        const int idx  = n - off;
        const int idxc = idx < 0 ? 0 : idx;
        const float4 kv = *(const float4*)(k + head_base + ((size_t)idxc << 6) + (j << 2));
        const float4 sv = *(const float4*)(se + (i << 6) + (j << 2));
        // q·(k + se_i) == q·k + q·se_i
        float acc = qv.x * (kv.x + sv.x) + qv.y * (kv.y + sv.y) +
                    qv.z * (kv.z + sv.z) + qv.w * (kv.w + sv.w);
        // reduce across the 16 lanes of this query group
        acc += __shfl_xor(acc, 1, 16);
        acc += __shfl_xor(acc, 2, 16);
        acc += __shfl_xor(acc, 4, 16);
        acc += __shfl_xor(acc, 8, 16);
        s[i] = (idx >= 0) ? acc * 0.125f + pb[(i << 4) + h] : NEG_BIG;
    }

    float m = s[0];
#pragma unroll
    for (int i = 1; i < 16; ++i) m = fmaxf(m, s[i]);

    float p[16];
    float l = 0.f;
#pragma unroll
    for (int i = 0; i < 16; ++i) {
        p[i] = (n >= OFFS[i]) ? __expf(s[i] - m) : 0.f;
        l += p[i];
    }

    float4 o = make_float4(0.f, 0.f, 0.f, 0.f);
#pragma unroll
    for (int i = 0; i < 16; ++i) {
        const int idx  = n - OFFS[i];
        const int idxc = idx < 0 ? 0 : idx;
        const float4 vv = *(const float4*)(v + head_base + ((size_t)idxc << 6) + (j << 2));
        o.x += p[i] * vv.x;
        o.y += p[i] * vv.y;
        o.z += p[i] * vv.z;
        o.w += p[i] * vv.w;
    }

    const float inv = (l > 0.f) ? 1.f / l : 0.f; // l==0 only when all offsets invalid (n==0) -> out 0
    o.x *= inv; o.y *= inv; o.z *= inv; o.w *= inv;
    *(float4*)(out + qoff) = o;
}

extern "C" void kernel_launch(void* const* d_in, const int* in_sizes, int n_in,
                              void* d_out, int out_size, void* d_ws, size_t ws_size,
                              hipStream_t stream) {
    const float* q  = (const float*)d_in[0];
    const float* k  = (const float*)d_in[1];
    const float* v  = (const float*)d_in[2];
    const float* pb = (const float*)d_in[3]; // (16 offsets, 16 heads)
    const float* se = (const float*)d_in[4]; // (16 offsets, 64 dims)
    float* out = (float*)d_out;

    dim3 grid(4096);
    dim3 block(256);
    dsqg_attn_kernel<<<grid, block, 0, stream>>>(q, k, v, pb, se, out);
}

// Round 2
// 41.248 us; speedup vs baseline: 1.2413x; 1.2413x over previous
//
#include <hip/hip_runtime.h>

#define NEG_BIG (-1e30f)

__global__ __launch_bounds__(256) void dsqg_attn_kernel(
    const float* __restrict__ q, const float* __restrict__ k,
    const float* __restrict__ v, const float* __restrict__ pb,
    const float* __restrict__ se, float* __restrict__ out)
{
    constexpr int OFFS[16] = {1, 3, 4, 13, 15, 21, 23, 28, 48, 64, 96, 192, 384, 512, 768, 1024};
    // grid: 16 heads * 128 blocks/head; block: 256 threads = 16 groups * 16 lanes
    // each group handles 2 queries: n0 = base+g and n1 = n0+16
    const int h  = blockIdx.x >> 7;                 // uniform -> SGPR
    const int g  = threadIdx.x >> 4;
    const int j  = threadIdx.x & 15;                // dim chunk: dims [4j, 4j+4)
    const int n0 = ((blockIdx.x & 127) << 5) + g;   // query A
    const int n1 = n0 + 16;                         // query B
    const size_t hb = (size_t)h << 18;              // h * 4096 * 64
    const int jo = j << 2;

    // pos_bias for this head: uniform scalar loads
    float pbv[16];
#pragma unroll
    for (int i = 0; i < 16; ++i) pbv[i] = pb[(i << 4) + h];

    const float4 qa = *(const float4*)(q + hb + ((size_t)n0 << 6) + jo);
    const float4 qb = *(const float4*)(q + hb + ((size_t)n1 << 6) + jo);

    float sa[16], sb[16];
#pragma unroll
    for (int i = 0; i < 16; ++i) {
        const int off = OFFS[i];
        const int ia = n0 - off, ib = n1 - off;
        const int iac = ia < 0 ? 0 : ia;
        const int ibc = ib < 0 ? 0 : ib;
        const float4 sv = *(const float4*)(se + (i << 6) + jo);
        const float4 ka = *(const float4*)(k + hb + ((size_t)iac << 6) + jo);
        const float4 kb = *(const float4*)(k + hb + ((size_t)ibc << 6) + jo);
        // q·(k + se_i) == q·k + q·se_i
        float accA = qa.x * (ka.x + sv.x) + qa.y * (ka.y + sv.y) +
                     qa.z * (ka.z + sv.z) + qa.w * (ka.w + sv.w);
        float accB = qb.x * (kb.x + sv.x) + qb.y * (kb.y + sv.y) +
                     qb.z * (kb.z + sv.z) + qb.w * (kb.w + sv.w);
        // two independent butterfly chains -> pipelined DS ops
        accA += __shfl_xor(accA, 1, 16);
        accB += __shfl_xor(accB, 1, 16);
        accA += __shfl_xor(accA, 2, 16);
        accB += __shfl_xor(accB, 2, 16);
        accA += __shfl_xor(accA, 4, 16);
        accB += __shfl_xor(accB, 4, 16);
        accA += __shfl_xor(accA, 8, 16);
        accB += __shfl_xor(accB, 8, 16);
        sa[i] = (ia >= 0) ? accA * 0.125f + pbv[i] : NEG_BIG;
        sb[i] = (ib >= 0) ? accB * 0.125f + pbv[i] : NEG_BIG;
    }

    float ma = sa[0], mb = sb[0];
#pragma unroll
    for (int i = 1; i < 16; ++i) { ma = fmaxf(ma, sa[i]); mb = fmaxf(mb, sb[i]); }

    float la = 0.f, lb = 0.f;
#pragma unroll
    for (int i = 0; i < 16; ++i) {
        sa[i] = (n0 >= OFFS[i]) ? __expf(sa[i] - ma) : 0.f;
        sb[i] = (n1 >= OFFS[i]) ? __expf(sb[i] - mb) : 0.f;
        la += sa[i];
        lb += sb[i];
    }

    float4 oa = make_float4(0.f, 0.f, 0.f, 0.f);
    float4 ob = make_float4(0.f, 0.f, 0.f, 0.f);
#pragma unroll
    for (int i = 0; i < 16; ++i) {
        const int off = OFFS[i];
        const int ia = n0 - off, ib = n1 - off;
        const int iac = ia < 0 ? 0 : ia;
        const int ibc = ib < 0 ? 0 : ib;
        const float4 va = *(const float4*)(v + hb + ((size_t)iac << 6) + jo);
        const float4 vb = *(const float4*)(v + hb + ((size_t)ibc << 6) + jo);
        oa.x += sa[i] * va.x; oa.y += sa[i] * va.y; oa.z += sa[i] * va.z; oa.w += sa[i] * va.w;
        ob.x += sb[i] * vb.x; ob.y += sb[i] * vb.y; ob.z += sb[i] * vb.z; ob.w += sb[i] * vb.w;
    }

    const float inva = (la > 0.f) ? 1.f / la : 0.f;
    const float invb = (lb > 0.f) ? 1.f / lb : 0.f;
    oa.x *= inva; oa.y *= inva; oa.z *= inva; oa.w *= inva;
    ob.x *= invb; ob.y *= invb; ob.z *= invb; ob.w *= invb;
    *(float4*)(out + hb + ((size_t)n0 << 6) + jo) = oa;
    *(float4*)(out + hb + ((size_t)n1 << 6) + jo) = ob;
}

extern "C" void kernel_launch(void* const* d_in, const int* in_sizes, int n_in,
                              void* d_out, int out_size, void* d_ws, size_t ws_size,
                              hipStream_t stream) {
    const float* q  = (const float*)d_in[0];
    const float* k  = (const float*)d_in[1];
    const float* v  = (const float*)d_in[2];
    const float* pb = (const float*)d_in[3]; // (16 offsets, 16 heads)
    const float* se = (const float*)d_in[4]; // (16 offsets, 64 dims)
    float* out = (float*)d_out;

    dim3 grid(2048);
    dim3 block(256);
    dsqg_attn_kernel<<<grid, block, 0, stream>>>(q, k, v, pb, se, out);
}